// Round 9
// baseline (211.112 us; speedup 1.0000x reference)
//
#include <hip/hip_runtime.h>
#include <math.h>

#define NN 20000
#define NE 640000
#define D  128
#define NSLICE 2500        // NN / 8 XCDs
#define NTILES 625         // NN / 32 rows per GEMM tile (exact)
#define SUBSEG 40          // per-(node, src-quartile) sub-segment depth
#define SEGSTRIDE 160      // 4 * SUBSEG entries per node
#define NCHUNK 640         // fill chunks
#define CHUNK 1000         // edges per chunk (640*1000 = NE)

typedef __attribute__((ext_vector_type(8))) short short8;
typedef __attribute__((ext_vector_type(4))) float floatx4;

static __device__ __forceinline__ unsigned short f2bf(float f) {
    union { float f; unsigned int u; } v; v.f = f;
    unsigned int u = v.u;
    u += 0x7fff + ((u >> 16) & 1);   // round-to-nearest-even
    return (unsigned short)(u >> 16);
}
static __device__ __forceinline__ unsigned int pack2bf(float a, float b) {
    return (unsigned int)f2bf(a) | ((unsigned int)f2bf(b) << 16);
}
static __device__ __forceinline__ float bf_lo(unsigned int u) {
    union { unsigned int i; float f; } v; v.i = u << 16; return v.f;
}
static __device__ __forceinline__ float bf_hi(unsigned int u) {
    union { unsigned int i; float f; } v; v.i = u & 0xffff0000u; return v.f;
}
static __device__ __forceinline__ float sigm(float x) { return 1.f / (1.f + __expf(-x)); }
static __device__ __forceinline__ float tanhx(float x) { return 1.f - 2.f / (__expf(2.f * x) + 1.f); }

// accumulate 8 bf16 values (one uint4 = 16 B) into 8 f32 accumulators.
// (function, not macro: R8's macro param `w` collided with uint4 member .w)
static __device__ __forceinline__ void acc8(float* a, uint4 v, float wgt) {
    a[0] += bf_lo(v.x) * wgt; a[1] += bf_hi(v.x) * wgt;
    a[2] += bf_lo(v.y) * wgt; a[3] += bf_hi(v.y) * wgt;
    a[4] += bf_lo(v.z) * wgt; a[5] += bf_hi(v.z) * wgt;
    a[6] += bf_lo(v.w) * wgt; a[7] += bf_hi(v.w) * wgt;
}

// Fused prep + CSR fill (unchanged — control). Src-quartile-binned bump
// allocation (q = src/5000, SUBSEG deep); X/H bf16 pack; coalesced weight
// transpose; bias fuse; XCD-sliced fill.
// Wsz layout (shorts): idx = ci*16384 + jg*4096 + col*8 + off, k = ci*32+jg*8+off.
__global__ void __launch_bounds__(256)
prep_fill_kernel(const int* __restrict__ src, const int* __restrict__ dst,
                 const float* __restrict__ ew, int* __restrict__ cnt4,
                 unsigned int* __restrict__ s_p,
                 const float4* __restrict__ X4, const float4* __restrict__ H4,
                 unsigned int* __restrict__ XH32,
                 const float* __restrict__ Wx_l, const float* __restrict__ Wx_r,
                 const float* __restrict__ Wh_l, const float* __restrict__ Wh_r,
                 const float* __restrict__ bx, const float* __restrict__ bh,
                 const float* __restrict__ bg,
                 unsigned short* __restrict__ Wsz, float* __restrict__ bias) {
    int tid = threadIdx.x, b = blockIdx.x;       // 5120 blocks x 256 threads

    int chunk = b >> 3, s = b & 7;
    int lo = s * NSLICE, hi = lo + NSLICE;
    int4 d4, sr4; float4 w4;
    bool fill = (tid < 250);
    if (fill) {
        int e0 = chunk * CHUNK + tid * 4;
        d4  = *(const int4*)(dst + e0);
        sr4 = *(const int4*)(src + e0);
        w4  = *(const float4*)(ew + e0);
    }

    if (b < 2560) {
        int t = b * 256 + tid;
        if (t < NE) {
            float4 x = X4[t];
            float4 h = H4[t];
            int n = t >> 5, q = t & 31;
            unsigned int* row = XH32 + n * 128;
            row[2 * q]          = pack2bf(x.x, x.y);
            row[2 * q + 1]      = pack2bf(x.z, x.w);
            row[64 + 2 * q]     = pack2bf(h.x, h.y);
            row[64 + 2 * q + 1] = pack2bf(h.z, h.w);
        }
    } else if (b < 2816) {
        int t = (b - 2560) * 256 + tid;      // < 65536
        int row = t >> 5;                    // row = g*512 + k
        int g = row >> 9, k = row & 511;
        int o = (t & 31) * 4;
        const float* Wb; int kk;
        if (k < 128)      { Wb = Wx_l; kk = k; }
        else if (k < 256) { Wb = Wx_r; kk = k - 128; }
        else if (k < 384) { Wb = Wh_l; kk = k - 256; }
        else              { Wb = Wh_r; kk = k - 384; }
        float4 w = *(const float4*)(Wb + g * 16384 + kk * 128 + o);
        int ci = k >> 5, jg = (k >> 3) & 3, off = k & 7;
        unsigned short* wp = Wsz + ci * 16384 + jg * 4096 + (g * 128 + o) * 8 + off;
        wp[0]  = f2bf(w.x);
        wp[8]  = f2bf(w.y);
        wp[16] = f2bf(w.z);
        wp[24] = f2bf(w.w);
        if (k == 0) {
            int j0 = g * 128 + o;
#pragma unroll
            for (int i = 0; i < 4; ++i)
                bias[j0 + i] = bx[j0 + i] + bh[j0 + i] + bg[j0 + i];
        }
    }

    if (fill) {
        int dv[4] = {d4.x, d4.y, d4.z, d4.w};
        int sv[4] = {sr4.x, sr4.y, sr4.z, sr4.w};
        float wv[4] = {w4.x, w4.y, w4.z, w4.w};
#pragma unroll
        for (int k = 0; k < 4; ++k) {
            int d = dv[k];
            if (d >= lo && d < hi) {
                int q = (int)((unsigned)sv[k] / 5000u);   // src window 0..3
                int p = atomicAdd(&cnt4[d * 4 + q], 1);
                if (p < SUBSEG)
                    s_p[d * SEGSTRIDE + q * SUBSEG + p] =
                        (unsigned int)sv[k] | ((unsigned int)f2bf(wv[k]) << 16);
            }
        }
    }
}

// R8/R9: FUSED aggregation + GEMM + peephole-LSTM. 625 blocks x 256 threads.
// Standalone agg (33 us) and gemm (41 us) were both latency-bound with ~75%
// idle issue slots, serialized through a 20 MB AGG HBM round-trip. The
// block's agg output IS its A-operand for K-chunks {aggX,aggH} — gather it
// locally into a 16 KB LDS image and never touch HBM with it.
//  Phase G: 8 threads/node x 32 nodes; thread owns a 64 B column chunk.
//    Edges from the binned segments (same q,i order -> per-column f32 sums
//    bit-identical to the standalone path). 2-edge software pipeline (8
//    loads in flight). /deg, pack bf16, write LDS XOR-swizzled
//    (ofs ^= (row&7)<<4 -> ds_read_b128 conflict-free; G4).
//  Loop A (it 0..7): A = XH rows (X then H) from global, ci = it+4+(it&4).
//  barrier (LDS writes long since landed; smooths gather imbalance).
//  Loop B (it 0..7): A = LDS agg image, ci = it+(it&4).
//  B frags direct-from-L2 (Wsz 512 KB is XCD-resident; R7 result); A and B
//  prefetched one iter ahead; 16 MFMA/iter; in-register LSTM epilogue.
// K-order change (X,H,aggX,aggH) only reorders f32 accumulation (~1e-7);
// absmax is bf16-quant dominated (stable 0.015625 across 4 agg rewrites).
__global__ void __launch_bounds__(256)
aggemm_lstm_kernel(const unsigned short* __restrict__ XH,
                   const int* __restrict__ cnt4,
                   const unsigned int* __restrict__ s_p,
                   const unsigned short* __restrict__ Wsz,
                   const float* __restrict__ bias,
                   const float* __restrict__ wc,
                   const float* __restrict__ C,
                   float* __restrict__ out) {
    __shared__ __align__(16) char sA[16384];   // [32 rows][256 shorts], swizzled

    int tid = threadIdx.x;
    int wv = tid >> 6, lane = tid & 63;
    int lm = lane & 15, lq = lane >> 4;
    int m0 = blockIdx.x * 32;

    // ---------------- Phase G: local aggregation ----------------
    {
        int rr = tid >> 3;                       // node-local row 0..31
        int cch = tid & 7;                       // 64 B column chunk
        int n = m0 + rr;
        int4 cn = *(const int4*)(cnt4 + n * 4);
        const unsigned int* segb = s_p + (size_t)n * SEGSTRIDE;
        const uint4* xb = (const uint4*)XH + cch * 4;   // + e*32 per edge
        float ac[32];
#pragma unroll
        for (int j = 0; j < 32; ++j) ac[j] = 0.f;
        int deg = cn.x + cn.y + cn.z + cn.w;
#pragma unroll
        for (int q = 0; q < 4; ++q) {
            int cq = (q == 0) ? cn.x : (q == 1) ? cn.y : (q == 2) ? cn.z : cn.w;
            int mq = (cq < SUBSEG) ? cq : SUBSEG;
            const unsigned int* seg = segb + q * SUBSEG;
            int i = 0;
            for (; i + 2 <= mq; i += 2) {        // 2-edge pipeline: 8 loads in flight
                unsigned int e0 = seg[i], e1 = seg[i + 1];
                const uint4* p0 = xb + (size_t)(e0 & 0xffff) * 32;
                const uint4* p1 = xb + (size_t)(e1 & 0xffff) * 32;
                uint4 v00 = p0[0], v01 = p0[1], v02 = p0[2], v03 = p0[3];
                uint4 v10 = p1[0], v11 = p1[1], v12 = p1[2], v13 = p1[3];
                float w0 = __int_as_float(e0 & 0xffff0000u);
                float w1 = __int_as_float(e1 & 0xffff0000u);
                acc8(ac +  0, v00, w0); acc8(ac +  8, v01, w0);
                acc8(ac + 16, v02, w0); acc8(ac + 24, v03, w0);
                acc8(ac +  0, v10, w1); acc8(ac +  8, v11, w1);
                acc8(ac + 16, v12, w1); acc8(ac + 24, v13, w1);
            }
            if (i < mq) {
                unsigned int e0 = seg[i];
                const uint4* p0 = xb + (size_t)(e0 & 0xffff) * 32;
                uint4 v00 = p0[0], v01 = p0[1], v02 = p0[2], v03 = p0[3];
                float w0 = __int_as_float(e0 & 0xffff0000u);
                acc8(ac +  0, v00, w0); acc8(ac +  8, v01, w0);
                acc8(ac + 16, v02, w0); acc8(ac + 24, v03, w0);
            }
        }
        float inv = (deg > 0) ? 1.0f / (float)deg : 1.0f;
        int sw = (rr & 7) << 4;
        int bb = rr * 512 + cch * 64;
        uint4 o0, o1, o2, o3;
        o0.x = pack2bf(ac[0] * inv, ac[1] * inv);   o0.y = pack2bf(ac[2] * inv, ac[3] * inv);
        o0.z = pack2bf(ac[4] * inv, ac[5] * inv);   o0.w = pack2bf(ac[6] * inv, ac[7] * inv);
        o1.x = pack2bf(ac[8] * inv, ac[9] * inv);   o1.y = pack2bf(ac[10] * inv, ac[11] * inv);
        o1.z = pack2bf(ac[12] * inv, ac[13] * inv); o1.w = pack2bf(ac[14] * inv, ac[15] * inv);
        o2.x = pack2bf(ac[16] * inv, ac[17] * inv); o2.y = pack2bf(ac[18] * inv, ac[19] * inv);
        o2.z = pack2bf(ac[20] * inv, ac[21] * inv); o2.w = pack2bf(ac[22] * inv, ac[23] * inv);
        o3.x = pack2bf(ac[24] * inv, ac[25] * inv); o3.y = pack2bf(ac[26] * inv, ac[27] * inv);
        o3.z = pack2bf(ac[28] * inv, ac[29] * inv); o3.w = pack2bf(ac[30] * inv, ac[31] * inv);
        *(uint4*)(sA + ((bb +  0) ^ sw)) = o0;
        *(uint4*)(sA + ((bb + 16) ^ sw)) = o1;
        *(uint4*)(sA + ((bb + 32) ^ sw)) = o2;
        *(uint4*)(sA + ((bb + 48) ^ sw)) = o3;
    }

    // ---------------- GEMM ----------------
    floatx4 acc[2][4][2];
#pragma unroll
    for (int mt = 0; mt < 2; ++mt)
#pragma unroll
        for (int g = 0; g < 4; ++g)
#pragma unroll
            for (int nt = 0; nt < 2; ++nt) acc[mt][g][nt] = (floatx4)(0.f);

    // per-thread bases: A rows m0+lm / m0+16+lm; B col = g*128+wv*32+nt*16+lm
    const unsigned short* aBase = XH + (size_t)(m0 + lm) * 256 + lq * 8;
    const unsigned short* wB = Wsz + lq * 4096 + (wv << 8) + lm * 8;

    short8 ca0, ca1, cb[8];
    // preload Loop A it=0: A offset 0 (X), ci=4
    ca0 = *(const short8*)(aBase);
    ca1 = *(const short8*)(aBase + 16 * 256);
#pragma unroll
    for (int g = 0; g < 4; ++g)
#pragma unroll
        for (int nt = 0; nt < 2; ++nt)
            cb[g * 2 + nt] = *(const short8*)(wB + 4 * 16384 + g * 1024 + nt * 128);

    // Loop A: A from global XH (it*32 shorts: X cols then H cols)
    for (int it = 0; it < 8; ++it) {
        short8 na0, na1, nb[8];
        if (it < 7) {
            const unsigned short* ar = aBase + (it + 1) * 32;
            na0 = *(const short8*)(ar);
            na1 = *(const short8*)(ar + 16 * 256);
            int ci = it + 5 + ((it + 1) & 4);    // ci(it+1) = (it+1)+4+((it+1)&4)
            const unsigned short* wb2 = wB + ci * 16384;
#pragma unroll
            for (int g = 0; g < 4; ++g)
#pragma unroll
                for (int nt = 0; nt < 2; ++nt)
                    nb[g * 2 + nt] = *(const short8*)(wb2 + g * 1024 + nt * 128);
        }
#pragma unroll
        for (int g = 0; g < 4; ++g)
#pragma unroll
            for (int nt = 0; nt < 2; ++nt) {
                acc[0][g][nt] = __builtin_amdgcn_mfma_f32_16x16x32_bf16(ca0, cb[g * 2 + nt], acc[0][g][nt], 0, 0, 0);
                acc[1][g][nt] = __builtin_amdgcn_mfma_f32_16x16x32_bf16(ca1, cb[g * 2 + nt], acc[1][g][nt], 0, 0, 0);
            }
        ca0 = na0; ca1 = na1;
#pragma unroll
        for (int k = 0; k < 8; ++k) cb[k] = nb[k];
    }

    // preload Loop B it=0 B frags (ci=0) before the barrier
#pragma unroll
    for (int g = 0; g < 4; ++g)
#pragma unroll
        for (int nt = 0; nt < 2; ++nt)
            cb[g * 2 + nt] = *(const short8*)(wB + g * 1024 + nt * 128);

    __syncthreads();   // agg image ready (written pre-Loop-A)

    // Loop B: A from swizzled LDS agg image (aggX cols then aggH cols)
    int swr = (lm & 7) << 4;
    for (int it = 0; it < 8; ++it) {
        short8 nb[8];
        if (it < 7) {
            int ci = it + 1 + ((it + 1) & 4);    // {1,2,3,8,9,10,11}
            const unsigned short* wb2 = wB + ci * 16384;
#pragma unroll
            for (int g = 0; g < 4; ++g)
#pragma unroll
                for (int nt = 0; nt < 2; ++nt)
                    nb[g * 2 + nt] = *(const short8*)(wb2 + g * 1024 + nt * 128);
        }
        int b0 = (lm * 512 + it * 64 + lq * 16) ^ swr;
        short8 la0 = *(const short8*)(sA + b0);
        short8 la1 = *(const short8*)(sA + b0 + 8192);   // row lm+16: same XOR
#pragma unroll
        for (int g = 0; g < 4; ++g)
#pragma unroll
            for (int nt = 0; nt < 2; ++nt) {
                acc[0][g][nt] = __builtin_amdgcn_mfma_f32_16x16x32_bf16(la0, cb[g * 2 + nt], acc[0][g][nt], 0, 0, 0);
                acc[1][g][nt] = __builtin_amdgcn_mfma_f32_16x16x32_bf16(la1, cb[g * 2 + nt], acc[1][g][nt], 0, 0, 0);
            }
#pragma unroll
        for (int k = 0; k < 8; ++k) cb[k] = nb[k];
    }

    // ---------------- LSTM epilogue (in-register) ----------------
    float bG[4][2], wP[3][2];
#pragma unroll
    for (int nt = 0; nt < 2; ++nt) {
        int cg0 = (wv << 5) + (nt << 4) + lm;
#pragma unroll
        for (int g = 0; g < 4; ++g) bG[g][nt] = bias[(g << 7) + cg0];
#pragma unroll
        for (int j = 0; j < 3; ++j) wP[j][nt] = wc[j * 128 + cg0];
    }

#pragma unroll
    for (int mt = 0; mt < 2; ++mt)
#pragma unroll
        for (int r = 0; r < 4; ++r) {
            int row = m0 + mt * 16 + lq * 4 + r;   // 625*32 == NN exact
#pragma unroll
            for (int nt = 0; nt < 2; ++nt) {
                int cg0 = (wv << 5) + (nt << 4) + lm;
                float c = C[(size_t)row * D + cg0];
                float pi = acc[mt][0][nt][r] + bG[0][nt] + wP[0][nt] * c;
                float pf = acc[mt][1][nt][r] + bG[1][nt] + wP[1][nt] * c;
                float pt = acc[mt][2][nt][r] + bG[2][nt];
                float po = acc[mt][3][nt][r] + bG[3][nt];
                float I = sigm(pi);
                float F = sigm(pf);
                float T = tanhx(pt);
                float cn = F * c + I * T;
                float O = sigm(po + wP[2][nt] * cn);
                out[(size_t)row * D + cg0] = O * tanhx(cn);
                out[(size_t)NN * D + (size_t)row * D + cg0] = cn;
            }
        }
}

extern "C" void kernel_launch(void* const* d_in, const int* in_sizes, int n_in,
                              void* d_out, int out_size, void* d_ws, size_t ws_size,
                              hipStream_t stream) {
    const float* X  = (const float*)d_in[0];
    const int* ei   = (const int*)d_in[1];
    const float* ew = (const float*)d_in[2];
    const float* H  = (const float*)d_in[3];
    const float* C  = (const float*)d_in[4];
    const float* Wx_l = (const float*)d_in[5];
    const float* Wx_r = (const float*)d_in[6];
    const float* bx   = (const float*)d_in[7];
    const float* Wh_l = (const float*)d_in[8];
    const float* Wh_r = (const float*)d_in[9];
    const float* bh   = (const float*)d_in[10];
    const float* wc   = (const float*)d_in[11];
    const float* bg   = (const float*)d_in[12];
    float* out = (float*)d_out;

    const int* src = ei;
    const int* dst = ei + NE;

    // workspace layout (16B aligned)
    char* ws = (char*)d_ws;
    int* cnt4 = (int*)(ws + 0);                               //    320,000 B
    unsigned int* s_p = (unsigned int*)(ws + 320128);         // 12,800,000 B
    unsigned short* XH  = (unsigned short*)(ws + 13120128);   // 10,240,000 B
    unsigned short* Wsz = (unsigned short*)(ws + 23360128);   //    524,288 B
    float* bias = (float*)(ws + 23884416);                    //      2,048 B

    hipMemsetAsync(cnt4, 0, NN * 4 * sizeof(int), stream);
    prep_fill_kernel<<<5120, 256, 0, stream>>>(src, dst, ew, cnt4, s_p,
                                               (const float4*)X, (const float4*)H,
                                               (unsigned int*)XH,
                                               Wx_l, Wx_r, Wh_l, Wh_r,
                                               bx, bh, bg, Wsz, bias);
    aggemm_lstm_kernel<<<NTILES, 256, 0, stream>>>(XH, cnt4, s_p, Wsz, bias,
                                                   wc, C, out);
}

// Round 10
// 197.370 us; speedup vs baseline: 1.0696x; 1.0696x over previous
//
#include <hip/hip_runtime.h>
#include <math.h>

#define NN 20000
#define NE 640000
#define D  128
#define NSLICE 2500        // NN / 8 XCDs
#define SUBSEG 40          // per-(node, src-quartile) sub-segment depth
#define SEGSTRIDE 160      // 4 * SUBSEG entries per node
#define CHUNK 1000         // edges per fill chunk (640*1000 = NE)

typedef __attribute__((ext_vector_type(8))) short short8;
typedef __attribute__((ext_vector_type(4))) float floatx4;

static __device__ __forceinline__ unsigned short f2bf(float f) {
    union { float f; unsigned int u; } v; v.f = f;
    unsigned int u = v.u;
    u += 0x7fff + ((u >> 16) & 1);   // round-to-nearest-even
    return (unsigned short)(u >> 16);
}
static __device__ __forceinline__ unsigned int pack2bf(float a, float b) {
    return (unsigned int)f2bf(a) | ((unsigned int)f2bf(b) << 16);
}
static __device__ __forceinline__ float bf_lo(unsigned int u) {
    union { unsigned int i; float f; } v; v.i = u << 16; return v.f;
}
static __device__ __forceinline__ float bf_hi(unsigned int u) {
    union { unsigned int i; float f; } v; v.i = u & 0xffff0000u; return v.f;
}
static __device__ __forceinline__ float sigm(float x) { return 1.f / (1.f + __expf(-x)); }
static __device__ __forceinline__ float tanhx(float x) { return 1.f - 2.f / (__expf(2.f * x) + 1.f); }

static __device__ __forceinline__ void load_lds16(const void* g, void* l) {
    __builtin_amdgcn_global_load_lds(
        (const __attribute__((address_space(1))) unsigned int*)g,
        (__attribute__((address_space(3))) unsigned int*)l, 16, 0, 0);
}

// Fused prep + CSR fill (R7 verbatim — control). Src-quartile-binned bump
// allocation (q = src/5000, SUBSEG deep); X/H bf16 pack; coalesced weight
// transpose; bias fuse; XCD-sliced fill.
// Wsz layout (shorts): idx = ci*16384 + jg*4096 + col*8 + off, k = ci*32+jg*8+off.
__global__ void __launch_bounds__(256)
prep_fill_kernel(const int* __restrict__ src, const int* __restrict__ dst,
                 const float* __restrict__ ew, int* __restrict__ cnt4,
                 unsigned int* __restrict__ s_p,
                 const float4* __restrict__ X4, const float4* __restrict__ H4,
                 unsigned int* __restrict__ XH32,
                 const float* __restrict__ Wx_l, const float* __restrict__ Wx_r,
                 const float* __restrict__ Wh_l, const float* __restrict__ Wh_r,
                 const float* __restrict__ bx, const float* __restrict__ bh,
                 const float* __restrict__ bg,
                 unsigned short* __restrict__ Wsz, float* __restrict__ bias) {
    int tid = threadIdx.x, b = blockIdx.x;       // 5120 blocks x 256 threads

    int chunk = b >> 3, s = b & 7;
    int lo = s * NSLICE, hi = lo + NSLICE;
    int4 d4, sr4; float4 w4;
    bool fill = (tid < 250);
    if (fill) {
        int e0 = chunk * CHUNK + tid * 4;
        d4  = *(const int4*)(dst + e0);
        sr4 = *(const int4*)(src + e0);
        w4  = *(const float4*)(ew + e0);
    }

    if (b < 2560) {
        int t = b * 256 + tid;
        if (t < NE) {
            float4 x = X4[t];
            float4 h = H4[t];
            int n = t >> 5, q = t & 31;
            unsigned int* row = XH32 + n * 128;
            row[2 * q]          = pack2bf(x.x, x.y);
            row[2 * q + 1]      = pack2bf(x.z, x.w);
            row[64 + 2 * q]     = pack2bf(h.x, h.y);
            row[64 + 2 * q + 1] = pack2bf(h.z, h.w);
        }
    } else if (b < 2816) {
        int t = (b - 2560) * 256 + tid;      // < 65536
        int row = t >> 5;                    // row = g*512 + k
        int g = row >> 9, k = row & 511;
        int o = (t & 31) * 4;
        const float* Wb; int kk;
        if (k < 128)      { Wb = Wx_l; kk = k; }
        else if (k < 256) { Wb = Wx_r; kk = k - 128; }
        else if (k < 384) { Wb = Wh_l; kk = k - 256; }
        else              { Wb = Wh_r; kk = k - 384; }
        float4 w = *(const float4*)(Wb + g * 16384 + kk * 128 + o);
        int ci = k >> 5, jg = (k >> 3) & 3, off = k & 7;
        unsigned short* wp = Wsz + ci * 16384 + jg * 4096 + (g * 128 + o) * 8 + off;
        wp[0]  = f2bf(w.x);
        wp[8]  = f2bf(w.y);
        wp[16] = f2bf(w.z);
        wp[24] = f2bf(w.w);
        if (k == 0) {
            int j0 = g * 128 + o;
#pragma unroll
            for (int i = 0; i < 4; ++i)
                bias[j0 + i] = bx[j0 + i] + bh[j0 + i] + bg[j0 + i];
        }
    }

    if (fill) {
        int dv[4] = {d4.x, d4.y, d4.z, d4.w};
        int sv[4] = {sr4.x, sr4.y, sr4.z, sr4.w};
        float wv[4] = {w4.x, w4.y, w4.z, w4.w};
#pragma unroll
        for (int k = 0; k < 4; ++k) {
            int d = dv[k];
            if (d >= lo && d < hi) {
                int q = (int)((unsigned)sv[k] / 5000u);   // src window 0..3
                int p = atomicAdd(&cnt4[d * 4 + q], 1);
                if (p < SUBSEG)
                    s_p[d * SEGSTRIDE + q * SUBSEG + p] =
                        (unsigned int)sv[k] | ((unsigned int)f2bf(wv[k]) << 16);
            }
        }
    }
}

// Aggregation (R7 verbatim — control): 5000 blocks, 66% occupancy; 4
// source-window passes (2.56 MB window fits per-XCD L2), in-register
// partials, scalarized seg/weight/address via readfirstlane(n).
__global__ void __launch_bounds__(256)
aggregate_kernel(const uint2* __restrict__ XH64,
                 const int* __restrict__ cnt4,
                 const unsigned int* __restrict__ s_p,
                 uint2* __restrict__ AGG64) {
    int wv = threadIdx.x >> 6, lane = threadIdx.x & 63;
    int b = blockIdx.x;                 // 0..4999
    int s = b & 7, j = b >> 3;          // j: 0..624
    int n = __builtin_amdgcn_readfirstlane(s * NSLICE + j * 4 + wv);
    int c0 = cnt4[n * 4 + 0];           // uniform -> scalar loads
    int c1 = cnt4[n * 4 + 1];
    int c2 = cnt4[n * 4 + 2];
    int c3 = cnt4[n * 4 + 3];
    int deg = c0 + c1 + c2 + c3;
    const unsigned int* segbase = s_p + (size_t)n * SEGSTRIDE;
    float a0 = 0.f, a1 = 0.f, a2 = 0.f, a3 = 0.f;

#pragma unroll
    for (int p = 0; p < 4; ++p) {
        int c = (p == 0) ? c0 : (p == 1) ? c1 : (p == 2) ? c2 : c3;
        int m = (c < SUBSEG) ? c : SUBSEG;
        const unsigned int* seg = segbase + p * SUBSEG;
        int i = 0;
        for (; i + 8 <= m; i += 8) {
            unsigned int e[8];
            uint2 u[8];
#pragma unroll
            for (int k = 0; k < 8; ++k) e[k] = seg[i + k];   // scalar
#pragma unroll
            for (int k = 0; k < 8; ++k)
                u[k] = XH64[(size_t)(e[k] & 0xffff) * 64 + lane];
#pragma unroll
            for (int k = 0; k < 8; ++k) {
                float w = __int_as_float(e[k] & 0xffff0000u);
                a0 += bf_lo(u[k].x) * w;
                a1 += bf_hi(u[k].x) * w;
                a2 += bf_lo(u[k].y) * w;
                a3 += bf_hi(u[k].y) * w;
            }
        }
        for (; i + 4 <= m; i += 4) {
            unsigned int e[4];
            uint2 u[4];
#pragma unroll
            for (int k = 0; k < 4; ++k) e[k] = seg[i + k];
#pragma unroll
            for (int k = 0; k < 4; ++k)
                u[k] = XH64[(size_t)(e[k] & 0xffff) * 64 + lane];
#pragma unroll
            for (int k = 0; k < 4; ++k) {
                float w = __int_as_float(e[k] & 0xffff0000u);
                a0 += bf_lo(u[k].x) * w;
                a1 += bf_hi(u[k].x) * w;
                a2 += bf_lo(u[k].y) * w;
                a3 += bf_hi(u[k].y) * w;
            }
        }
        for (; i < m; ++i) {
            unsigned int e = seg[i];
            float w = __int_as_float(e & 0xffff0000u);
            uint2 u = XH64[(size_t)(e & 0xffff) * 64 + lane];
            a0 += bf_lo(u.x) * w;
            a1 += bf_hi(u.x) * w;
            a2 += bf_lo(u.y) * w;
            a3 += bf_hi(u.y) * w;
        }
    }

    float inv = (deg > 0) ? 1.0f / (float)deg : 1.0f;
    uint2 r;
    r.x = pack2bf(a0 * inv, a1 * inv);
    r.y = pack2bf(a2 * inv, a3 * inv);
    AGG64[(size_t)n * 64 + lane] = r;
}

// R10 GEMM + peephole-LSTM: M=64 tile + one-shot LDS A-panels.
// Line-count audit of R7 (41 us): ~160 L2 line-requests/iter/wave x 16
// iters x 5000 waves ~ 20M requests — VMEM request/L2-traffic bound.
// Fixes: (1) M=64, half-N split -> 626 blocks: B L2 traffic halves to
// 160 MB, B requests halve; (2) XH+AGG A-panels (64 KB LDS) staged ONCE
// via global_load_lds with PRE-SWIZZLED source offsets (linear LDS dest,
// read with ofs ^ (row&7)<<4 — R9-verified pattern), one barrier total;
// per-iter A = 4 ds_read_b128, no more 16-line row-gathers; (3) 16
// cols/wave -> acc = 4x4 floatx4 = 64 VGPR.
// K-order: it 0..7 = XH panel (X,H; ci=it+4+(it&4)); it 8..15 = AGG panel
// (aggX,aggH; ci=(it-8)+((it-8)&4)). B frags direct from L2 (R7 scheme),
// 1-deep prefetch. In-register LSTM epilogue, stores guarded (row<NN:
// last tile covers 19968..20031).
__global__ void __launch_bounds__(256)
gemm_lstm_kernel(const unsigned short* __restrict__ XH,
                 const unsigned short* __restrict__ AGG,
                 const unsigned short* __restrict__ Wsz,
                 const float* __restrict__ bias,
                 const float* __restrict__ wc,
                 const float* __restrict__ C,
                 float* __restrict__ out) {
    __shared__ __align__(16) char sA[65536];   // [0,32K)=XH panel, [32K,64K)=AGG

    int tid = threadIdx.x;
    int wv = tid >> 6, lane = tid & 63;
    int lm = lane & 15, lq = lane >> 4;
    int bid = blockIdx.x;                 // 626 = 313 m-tiles x 2 halves
    int m0 = (bid >> 1) * 64;
    int hb = (bid & 1) * 512;             // half-offset in shorts (64 cols * 8)

    // ---- stage A panels (once): wave wv stages local rows [wv*16, wv*16+16)
    // of both panels; per instr 64 lanes write 1 KB linear LDS (2 rows),
    // source offset pre-swizzled so reads use ofs ^ ((row&7)<<4).
    {
        int lrow = (lane >> 5);                       // 0/1 within pair
        int gofs = ((lane & 31) * 16) ^ ((lrow & 7) << 4);  // bytes (pair rows: row&7 == lrow&7 pattern below)
#pragma unroll
        for (int j = 0; j < 8; ++j) {
            int r0 = wv * 16 + j * 2;                 // pair base row (even)
            int rw = r0 + lrow;                       // this lane's row
            int go = ((lane & 31) * 16) ^ ((rw & 7) << 4);
            load_lds16(XH + (size_t)(m0 + rw) * 256 + (go >> 1),
                       sA + r0 * 512);
            load_lds16(AGG + (size_t)(m0 + rw) * 256 + (go >> 1),
                       sA + 32768 + r0 * 512);
        }
        (void)gofs; (void)lrow;
    }

    floatx4 acc[4][4];
#pragma unroll
    for (int mt = 0; mt < 4; ++mt)
#pragma unroll
        for (int g = 0; g < 4; ++g) acc[mt][g] = (floatx4)(0.f);

    // B base: col = g*128 + hb/8 + wv*16 + lm, k-group jg = lq
    const unsigned short* wB = Wsz + lq * 4096 + hb + ((wv << 4) + lm) * 8;

    // preload B for it=0 (ci=4) — independent of LDS, overlaps staging
    short8 cb0 = *(const short8*)(wB + 4 * 16384);
    short8 cb1 = *(const short8*)(wB + 4 * 16384 + 1024);
    short8 cb2 = *(const short8*)(wB + 4 * 16384 + 2048);
    short8 cb3 = *(const short8*)(wB + 4 * 16384 + 3072);

    __syncthreads();   // drains staging vmcnt; A panels ready

    int swr = (lm & 7) << 4;
    for (int it = 0; it < 16; ++it) {
        short8 nb0, nb1, nb2, nb3;
        if (it < 15) {
            int itn = it + 1;
            int ci = (itn < 8) ? (itn + 4 + (itn & 4)) : ((itn - 8) + ((itn - 8) & 4));
            const unsigned short* wb2 = wB + ci * 16384;
            nb0 = *(const short8*)(wb2);
            nb1 = *(const short8*)(wb2 + 1024);
            nb2 = *(const short8*)(wb2 + 2048);
            nb3 = *(const short8*)(wb2 + 3072);
        }
        int pbase = (it < 8) ? 0 : 32768;
        int koff = (it & 7) * 64 + lq * 16;
#pragma unroll
        for (int mt = 0; mt < 4; ++mt) {
            int b0 = pbase + (mt * 16 + lm) * 512 + (koff ^ swr);
            short8 a = *(const short8*)(sA + b0);
            acc[mt][0] = __builtin_amdgcn_mfma_f32_16x16x32_bf16(a, cb0, acc[mt][0], 0, 0, 0);
            acc[mt][1] = __builtin_amdgcn_mfma_f32_16x16x32_bf16(a, cb1, acc[mt][1], 0, 0, 0);
            acc[mt][2] = __builtin_amdgcn_mfma_f32_16x16x32_bf16(a, cb2, acc[mt][2], 0, 0, 0);
            acc[mt][3] = __builtin_amdgcn_mfma_f32_16x16x32_bf16(a, cb3, acc[mt][3], 0, 0, 0);
        }
        cb0 = nb0; cb1 = nb1; cb2 = nb2; cb3 = nb3;
    }

    // ---- LSTM epilogue (in-register) ----
    int cg0 = (hb >> 3) + (wv << 4) + lm;
    float bG[4], wP[3];
#pragma unroll
    for (int g = 0; g < 4; ++g) bG[g] = bias[(g << 7) + cg0];
#pragma unroll
    for (int j = 0; j < 3; ++j) wP[j] = wc[j * 128 + cg0];

#pragma unroll
    for (int mt = 0; mt < 4; ++mt)
#pragma unroll
        for (int r = 0; r < 4; ++r) {
            int row = m0 + mt * 16 + lq * 4 + r;
            if (row < NN) {
                float c = C[(size_t)row * D + cg0];
                float pi = acc[mt][0][r] + bG[0] + wP[0] * c;
                float pf = acc[mt][1][r] + bG[1] + wP[1] * c;
                float pt = acc[mt][2][r] + bG[2];
                float po = acc[mt][3][r] + bG[3];
                float I = sigm(pi);
                float F = sigm(pf);
                float T = tanhx(pt);
                float cn = F * c + I * T;
                float O = sigm(po + wP[2] * cn);
                out[(size_t)row * D + cg0] = O * tanhx(cn);
                out[(size_t)NN * D + (size_t)row * D + cg0] = cn;
            }
        }
}

extern "C" void kernel_launch(void* const* d_in, const int* in_sizes, int n_in,
                              void* d_out, int out_size, void* d_ws, size_t ws_size,
                              hipStream_t stream) {
    const float* X  = (const float*)d_in[0];
    const int* ei   = (const int*)d_in[1];
    const float* ew = (const float*)d_in[2];
    const float* H  = (const float*)d_in[3];
    const float* C  = (const float*)d_in[4];
    const float* Wx_l = (const float*)d_in[5];
    const float* Wx_r = (const float*)d_in[6];
    const float* bx   = (const float*)d_in[7];
    const float* Wh_l = (const float*)d_in[8];
    const float* Wh_r = (const float*)d_in[9];
    const float* bh   = (const float*)d_in[10];
    const float* wc   = (const float*)d_in[11];
    const float* bg   = (const float*)d_in[12];
    float* out = (float*)d_out;

    const int* src = ei;
    const int* dst = ei + NE;

    // workspace layout (16B aligned), ~34.1 MB
    char* ws = (char*)d_ws;
    int* cnt4 = (int*)(ws + 0);                               //    320,000 B
    unsigned int* s_p = (unsigned int*)(ws + 320128);         // 12,800,000 B
    unsigned short* XH  = (unsigned short*)(ws + 13120128);   // 10,240,000 B
    unsigned short* AGG = (unsigned short*)(ws + 23360128);   // 10,240,000 B
    unsigned short* Wsz = (unsigned short*)(ws + 33600128);   //    524,288 B
    float* bias = (float*)(ws + 34124416);                    //      2,048 B

    hipMemsetAsync(cnt4, 0, NN * 4 * sizeof(int), stream);
    prep_fill_kernel<<<5120, 256, 0, stream>>>(src, dst, ew, cnt4, s_p,
                                               (const float4*)X, (const float4*)H,
                                               (unsigned int*)XH,
                                               Wx_l, Wx_r, Wh_l, Wh_r,
                                               bx, bh, bg, Wsz, bias);
    aggregate_kernel<<<NN / 4, 256, 0, stream>>>((const uint2*)XH, cnt4, s_p,
                                                 (uint2*)AGG);
    gemm_lstm_kernel<<<626, 256, 0, stream>>>(XH, AGG, Wsz, bias, wc, C, out);
}